// Round 9
// baseline (399.899 us; speedup 1.0000x reference)
//
#include <hip/hip_runtime.h>

#define EMB 768
#define NH 12
#define HD 64
#define BB 32
#define NN 1024
// log2(e)/sqrt(12): Q pre-scale so QK^T is in log2 domain
#define QSCALE 0.41647025f

typedef _Float16 h8 __attribute__((ext_vector_type(8)));
typedef _Float16 h4 __attribute__((ext_vector_type(4)));
typedef _Float16 h2 __attribute__((ext_vector_type(2)));
typedef float f4 __attribute__((ext_vector_type(4)));

static __device__ __forceinline__ f4 mfma16(h8 a, h8 b, f4 c) {
  return __builtin_amdgcn_mfma_f32_16x16x32_f16(a, b, c, 0, 0, 0);
}

static __device__ __forceinline__ h2 cvt_pk(float a, float b) {
  return __builtin_bit_cast(h2, __builtin_amdgcn_cvt_pkrtz(a, b));
}

static __device__ __forceinline__ float exp2a(float x) {
#if __has_builtin(__builtin_amdgcn_exp2f)
  return __builtin_amdgcn_exp2f(x);
#else
  float r;
  asm("v_exp_f32 %0, %1\n\ts_nop 1" : "=v"(r) : "v"(x));
  return r;
#endif
}

// async global->LDS, 16B per lane; LDS dest = wave-uniform base + lane*16
static __device__ __forceinline__ void gload16(const _Float16* g, _Float16* lds) {
  __builtin_amdgcn_global_load_lds(
      (const __attribute__((address_space(1))) void*)g,
      (__attribute__((address_space(3))) void*)lds, 16, 0, 0);
}

// ---------------- X f32 -> f16 ----------------
__global__ __launch_bounds__(256) void k_cvt(const float* __restrict__ X,
                                             _Float16* __restrict__ Xh, int n4) {
  int i = blockIdx.x * 256 + threadIdx.x;
  if (i >= n4) return;
  float4 v = ((const float4*)X)[i];
  h4 o = {(_Float16)v.x, (_Float16)v.y, (_Float16)v.z, (_Float16)v.w};
  ((h4*)Xh)[i] = o;
}

// ---------------- W (768x768 f32) -> W^T f16, all three ----------------
__global__ __launch_bounds__(256) void k_wt(const float* __restrict__ W0,
                                            const float* __restrict__ W1,
                                            const float* __restrict__ W2,
                                            _Float16* __restrict__ Wt) {
  const float* W = blockIdx.z == 0 ? W0 : (blockIdx.z == 1 ? W1 : W2);
  _Float16* dst = Wt + (size_t)blockIdx.z * EMB * EMB;
  __shared__ float tile[64][65];
  const int t = threadIdx.x;
  const int r0 = blockIdx.y * 64, c0 = blockIdx.x * 64;
  const int r = t >> 4, c4 = (t & 15) * 4;
#pragma unroll
  for (int i = 0; i < 4; ++i) {
    const float4 v = *(const float4*)&W[(size_t)(r0 + r + 16 * i) * EMB + c0 + c4];
    tile[r + 16 * i][c4 + 0] = v.x; tile[r + 16 * i][c4 + 1] = v.y;
    tile[r + 16 * i][c4 + 2] = v.z; tile[r + 16 * i][c4 + 3] = v.w;
  }
  __syncthreads();
  const int cc = t >> 2, rr = (t & 3) * 16;
#pragma unroll
  for (int half = 0; half < 2; ++half) {
    h8 o;
#pragma unroll
    for (int j = 0; j < 8; ++j) o[j] = (_Float16)tile[rr + half * 8 + j][cc];
    *(h8*)&dst[(size_t)(c0 + cc) * EMB + r0 + rr + half * 8] = o;
  }
}

// ---------------- fused QKV GEMM: [32768 x 768] @ [768 x 2304] ----------------
// m97-pattern: BK=64, SINGLE-buffer LDS (32KB -> 5 blocks/CU) via global_load_lds w16,
// linear LDS + inverse-swizzled global source + swizzled ds_read_b128 (rule #21).
__global__ __launch_bounds__(256) void k_projf(const _Float16* __restrict__ Xh,
                                               const _Float16* __restrict__ Wt,
                                               const float* __restrict__ bq,
                                               const float* __restrict__ bk,
                                               const float* __restrict__ bv,
                                               _Float16* __restrict__ Qw,
                                               _Float16* __restrict__ Kw,
                                               _Float16* __restrict__ Vtmp) {
  __shared__ _Float16 As[128 * 64];  // 16KB
  __shared__ _Float16 Bs[128 * 64];  // 16KB
  const int t = threadIdx.x;
  const int w = t >> 6, l = t & 63;
  const int wm = w >> 1, wn = w & 1;
  const int p = l & 15, g = l >> 4;
  const int by = blockIdx.x;            // n-tile 0..17
  const int m0 = blockIdx.y * 128;      // m-tile 0..255
  const int n0 = by * 128;              // into flat Wt [2304][768]

  f4 acc[4][4];
#pragma unroll
  for (int mf = 0; mf < 4; ++mf)
#pragma unroll
    for (int nf = 0; nf < 4; ++nf) acc[mf][nf] = f4{0.f, 0.f, 0.f, 0.f};

  // staging geometry: lane l covers row (l>>3) of its 8-row segment, chunk (l&7)
  const int lrow = l >> 3, lch = (l & 7) ^ (l >> 3);  // inverse-swizzled source chunk

  for (int kt = 0; kt < 12; ++kt) {
    const int k0 = kt * 64;
#pragma unroll
    for (int i = 0; i < 4; ++i) {
      const int seg = (w << 2) | i;
      const int grow = (seg << 3) | lrow;
      gload16(Xh + (size_t)(m0 + grow) * EMB + k0 + lch * 8, As + seg * 512);
      gload16(Wt + (size_t)(n0 + grow) * EMB + k0 + lch * 8, Bs + seg * 512);
    }
    __syncthreads();  // drains vmcnt: staged tile visible
    const char* asb = (const char*)&As[0];
    const char* bsb = (const char*)&Bs[0];
#pragma unroll
    for (int ks = 0; ks < 2; ++ks) {
      h8 af[4], bf[4];
#pragma unroll
      for (int mf = 0; mf < 4; ++mf)
        af[mf] = *(const h8*)(asb + ((wm * 64 + mf * 16 + p) << 7) +
                              ((((ks << 2) | g) ^ (p & 7)) << 4));
#pragma unroll
      for (int nf = 0; nf < 4; ++nf)
        bf[nf] = *(const h8*)(bsb + ((wn * 64 + nf * 16 + p) << 7) +
                              ((((ks << 2) | g) ^ (p & 7)) << 4));
#pragma unroll
      for (int mf = 0; mf < 4; ++mf)
#pragma unroll
        for (int nf = 0; nf < 4; ++nf) acc[mf][nf] = mfma16(af[mf], bf[nf], acc[mf][nf]);
    }
    __syncthreads();  // all reads done before next stage overwrites
  }

  // epilogue: z-select (tiles never straddle the 768 boundary: 768 % 128 == 0)
  const int z = by / 6;
  const int nl0 = (by % 6) * 128;
  const float* bias = z == 0 ? bq : (z == 1 ? bk : bv);
  _Float16* Outz = z == 0 ? Qw : (z == 1 ? Kw : Vtmp);
  const float scale = z == 0 ? QSCALE : 1.0f;
#pragma unroll
  for (int nf = 0; nf < 4; ++nf) {
    const int C = nl0 + wn * 64 + nf * 16 + p;
    const float bvv = bias[C];
    const int h = C >> 6, e = C & 63;
#pragma unroll
    for (int mf = 0; mf < 4; ++mf) {
#pragma unroll
      for (int r = 0; r < 4; ++r) {
        const int R = m0 + wm * 64 + mf * 16 + g * 4 + r;
        const int b = R >> 10, tok = R & 1023;
        Outz[((size_t)(b * NH + h) * NN + tok) * HD + e] = (_Float16)((acc[mf][nf][r] + bvv) * scale);
      }
    }
  }
}

// ---------------- column stats + fused V scale/transpose ----------------
// l~_j = sum_i 2^S'; MT = log2(max_j l~); Vt[bh][e][j] = V[bh][j][e] * 2^MT / l~_j
__global__ __launch_bounds__(256) void k_stats(const _Float16* __restrict__ Q,
                                               const _Float16* __restrict__ K,
                                               const _Float16* __restrict__ Vtmp,
                                               float* __restrict__ MT,
                                               _Float16* __restrict__ Vt) {
  const int bh = blockIdx.x * 48 + (blockIdx.y >> 3);   // XCD-aware: bx = XCD
  const int jt = blockIdx.y & 7;
  const int j0 = jt * 128;
  __shared__ __align__(16) char SMEM[35080];
  _Float16* Ks = (_Float16*)SMEM;              // 16KB [128][64] swizzled
  _Float16* Qs = (_Float16*)(SMEM + 16384);    // 16KB
  float* Lj    = (float*)(SMEM + 32768);       // 512B
  float* reds  = (float*)(SMEM + 33280);       // 1KB [2][128]
  float* MsShp = (float*)(SMEM + 34312);       // 4B
  _Float16 (*Vtile)[72] = (_Float16(*)[72])SMEM;  // alias Ks after main loop: [64][72]=9216B
  const _Float16* Qb = Q + (size_t)bh * NN * HD;
  const _Float16* Kb = K + (size_t)bh * NN * HD;
  const int t = threadIdx.x, w = t >> 6, l = t & 63;
  const int wi = w >> 1, wj = w & 1;
  const int p = l & 15, g = l >> 4;
  // staging geometry (same as k_projf)
  const int lrow = l >> 3, lch = (l & 7) ^ (l >> 3);

  // K tile staged once
#pragma unroll
  for (int i = 0; i < 4; ++i) {
    const int seg = (w << 2) | i;
    const int grow = (seg << 3) | lrow;
    gload16(Kb + (size_t)(j0 + grow) * HD + lch * 8, Ks + seg * 512);
  }
  if (t < 128) Lj[t] = 0.f;
  __syncthreads();

  const char* ksb = (const char*)Ks;
  const char* qsb = (const char*)Qs;
  for (int i0 = 0; i0 < NN; i0 += 128) {
#pragma unroll
    for (int i = 0; i < 4; ++i) {
      const int seg = (w << 2) | i;
      const int grow = (seg << 3) | lrow;
      gload16(Qb + (size_t)(i0 + grow) * HD + lch * 8, Qs + seg * 512);
    }
    __syncthreads();  // drains gload: Qs ready
    f4 s[4][4];
#pragma unroll
    for (int mf = 0; mf < 4; ++mf)
#pragma unroll
      for (int nf = 0; nf < 4; ++nf) s[mf][nf] = f4{0.f, 0.f, 0.f, 0.f};
#pragma unroll
    for (int ks = 0; ks < 2; ++ks) {
      h8 af[4], bf[4];
#pragma unroll
      for (int mf = 0; mf < 4; ++mf)
        af[mf] = *(const h8*)(qsb + ((wi * 64 + mf * 16 + p) << 7) + ((((ks << 2) | g) ^ (p & 7)) << 4));
#pragma unroll
      for (int nf = 0; nf < 4; ++nf)
        bf[nf] = *(const h8*)(ksb + ((wj * 64 + nf * 16 + p) << 7) + ((((ks << 2) | g) ^ (p & 7)) << 4));
#pragma unroll
      for (int mf = 0; mf < 4; ++mf)
#pragma unroll
        for (int nf = 0; nf < 4; ++nf) s[mf][nf] = mfma16(af[mf], bf[nf], s[mf][nf]);
    }
    // direct f32 exp-sum over i (no max needed: |S'| bounded, f32 range ample)
#pragma unroll
    for (int nf = 0; nf < 4; ++nf) {
      float cs = 0.f;
#pragma unroll
      for (int mf = 0; mf < 4; ++mf)
#pragma unroll
        for (int r = 0; r < 4; ++r) cs += exp2a(s[mf][nf][r]);
      cs += __shfl_xor(cs, 16);
      cs += __shfl_xor(cs, 32);
      if (l < 16) reds[wi * 128 + wj * 64 + nf * 16 + l] = cs;
    }
    __syncthreads();
    if (t < 128) Lj[t] += reds[t] + reds[128 + t];
    __syncthreads();  // also guards Qs overwrite next iter
  }
  // tail: M* = log2(max_j l~_j)  (guarantees P = 2^(S'-M*) <= 1)
  if (w == 0) {
    float mv = fmaxf(Lj[l], Lj[l + 64]);
#pragma unroll
    for (int d = 32; d; d >>= 1) mv = fmaxf(mv, __shfl_xor(mv, d));
    if (l == 0) { MsShp[0] = __log2f(mv); MT[bh * 8 + jt] = MsShp[0]; }
  }
  __syncthreads();
  const float rmsc = exp2a(MsShp[0]);  // 2^M*;  V' = V * 2^M* / l~_j

  // fused V scale + transpose: rows j0..j0+127, two 64-row halves via Vtile (aliases Ks)
  const _Float16* Vb = Vtmp + (size_t)bh * NN * HD;
  _Float16* Vo = Vt + (size_t)bh * HD * NN;
  const int jr = t >> 3, c8 = (t & 7) * 8;
#pragma unroll
  for (int half = 0; half < 2; ++half) {
#pragma unroll
    for (int i = 0; i < 2; ++i) {
      const int jl = half * 64 + jr + 32 * i;
      const float inv = rmsc / Lj[jl];
      h8 v = *(const h8*)&Vb[(size_t)(j0 + jl) * HD + c8];
      h8 o;
#pragma unroll
      for (int j = 0; j < 8; ++j) o[j] = (_Float16)((float)v[j] * inv);
      *(h8*)&Vtile[jr + 32 * i][c8] = o;
    }
    __syncthreads();
#pragma unroll
    for (int i = 0; i < 2; ++i) {
      h8 o;
#pragma unroll
      for (int j = 0; j < 8; ++j) o[j] = Vtile[c8 + j][jr + 32 * i];
      *(h8*)&Vo[(size_t)(jr + 32 * i) * NN + j0 + half * 64 + c8] = o;
    }
    __syncthreads();
  }
}

// ---------------- output: out = 2^(S' - M*) @ V'  (S^T trick; 2 i-tiles/block; unroll-4) ---------
__global__ __launch_bounds__(256) void k_out(const _Float16* __restrict__ Q,
                                             const _Float16* __restrict__ K,
                                             const _Float16* __restrict__ Vt,
                                             const float* __restrict__ MT,
                                             float* __restrict__ Out) {
  const int bh = blockIdx.x * 48 + (blockIdx.y >> 2);   // XCD-aware: bx = XCD
  const int i0 = (blockIdx.y & 3) * 256;
  const int b = bh / NH, h = bh % NH;
  __shared__ _Float16 Ks[2][32][64];      // [buf][j][e], 128B rows, swz mask 7
  __shared__ _Float16 Vts[2][64][32];     // [buf][e][j], 64B rows, swz (row>>1)&3
  __shared__ _Float16 Ps[4][2][32][32];   // [wave][it][i][j], wave-private
  const _Float16* Qb = Q + (size_t)bh * NN * HD;
  const _Float16* Kb = K + (size_t)bh * NN * HD;
  const _Float16* Vb = Vt + (size_t)bh * HD * NN;
  const int t = threadIdx.x, w = t >> 6, l = t & 63;
  const int p = l & 15, g = l >> 4;
  char* psb[2] = {(char*)&Ps[w][0][0][0], (char*)&Ps[w][1][0][0]};

  // Q B-frags for both i-tiles (col i = i0 + it*128 + w*32 + f*16 + p)
  h8 bq[2][2][2];
#pragma unroll
  for (int it = 0; it < 2; ++it)
#pragma unroll
    for (int f = 0; f < 2; ++f)
#pragma unroll
      for (int ks = 0; ks < 2; ++ks)
        bq[it][f][ks] = *(const h8*)&Qb[(size_t)(i0 + it * 128 + w * 32 + f * 16 + p) * HD + ks * 32 + g * 8];

  f4 oacc[2][4][2];  // [it][ef][if] -> D[e][i]
#pragma unroll
  for (int it = 0; it < 2; ++it)
#pragma unroll
    for (int ef = 0; ef < 4; ++ef)
#pragma unroll
      for (int f = 0; f < 2; ++f) oacc[it][ef][f] = f4{0.f, 0.f, 0.f, 0.f};

  // staging: K 32x64 (row kr, chunk kc), V 64x32 (row vr, chunk vc)
  const int kr = t >> 3, kc = t & 7;
  const int vr = t >> 2, vc = t & 3;

  h8 kreg = *(const h8*)&Kb[(size_t)kr * HD + kc * 8];
  h8 vreg = *(const h8*)&Vb[(size_t)vr * NN + vc * 8];
  *(h8*)((char*)&Ks[0][0][0] + (kr << 7) + ((kc ^ (kr & 7)) << 4)) = kreg;
  *(h8*)((char*)&Vts[0][0][0] + (vr << 6) + ((vc ^ ((vr >> 1) & 3)) << 4)) = vreg;

  for (int jt4 = 0; jt4 < 8; ++jt4) {
    const float Mstar = MT[bh * 8 + jt4];
#pragma unroll
    for (int u = 0; u < 4; ++u) {
      const int jt = jt4 * 4 + u;
      const int cur = u & 1;  // jt4*4 even -> jt&1 == u&1 (static)
      char* ksb = (char*)&Ks[cur][0][0];
      char* vsb = (char*)&Vts[cur][0][0];
      __syncthreads();  // staged buf[cur] visible; prev reads of buf[cur^1] done
      if (jt + 1 < 32) {
        const int j0n = (jt + 1) * 32;
        kreg = *(const h8*)&Kb[(size_t)(j0n + kr) * HD + kc * 8];
        vreg = *(const h8*)&Vb[(size_t)vr * NN + j0n + vc * 8];
      }

      // shared fragments (reused by both i-tiles)
      h8 ak[2][2], av[4];
#pragma unroll
      for (int ks = 0; ks < 2; ++ks)
#pragma unroll
        for (int jf = 0; jf < 2; ++jf)
          ak[ks][jf] = *(const h8*)(ksb + ((jf * 16 + p) << 7) + ((((ks << 2) | g) ^ (p & 7)) << 4));
#pragma unroll
      for (int ef = 0; ef < 4; ++ef)
        av[ef] = *(const h8*)(vsb + ((ef * 16 + p) << 6) + ((g ^ ((p >> 1) & 3)) << 4));

      // per i-tile: S'^T, exp, P write
#pragma unroll
      for (int it = 0; it < 2; ++it) {
        f4 s[2][2];
#pragma unroll
        for (int f = 0; f < 2; ++f)
#pragma unroll
          for (int jf = 0; jf < 2; ++jf) s[f][jf] = f4{-Mstar, -Mstar, -Mstar, -Mstar};
#pragma unroll
        for (int ks = 0; ks < 2; ++ks)
#pragma unroll
          for (int f = 0; f < 2; ++f)
#pragma unroll
            for (int jf = 0; jf < 2; ++jf) s[f][jf] = mfma16(ak[ks][jf], bq[it][f][ks], s[f][jf]);
#pragma unroll
        for (int f = 0; f < 2; ++f)
#pragma unroll
          for (int jf = 0; jf < 2; ++jf) {
            const f4 sv = s[f][jf];
            h2 lo = cvt_pk(exp2a(sv[0]), exp2a(sv[1]));
            h2 hi = cvt_pk(exp2a(sv[2]), exp2a(sv[3]));
            h4 pw; pw[0] = lo[0]; pw[1] = lo[1]; pw[2] = hi[0]; pw[3] = hi[1];
            *(h4*)(psb[it] + ((f * 16 + p) << 6) +
                   (((2 * jf + (g >> 1)) ^ ((p >> 1) & 3)) << 4) + ((g & 1) << 3)) = pw;
          }
      }
      // wave-private P: DS in-order per wave; insurance wait + scheduling fence
      asm volatile("s_waitcnt lgkmcnt(0)" ::: "memory");
      __builtin_amdgcn_sched_barrier(0);

      // PV for both i-tiles
#pragma unroll
      for (int it = 0; it < 2; ++it) {
        h8 bp[2];
#pragma unroll
        for (int f = 0; f < 2; ++f)
          bp[f] = *(const h8*)(psb[it] + ((f * 16 + p) << 6) + ((g ^ ((p >> 1) & 3)) << 4));
#pragma unroll
        for (int ef = 0; ef < 4; ++ef)
#pragma unroll
          for (int f = 0; f < 2; ++f) oacc[it][ef][f] = mfma16(av[ef], bp[f], oacc[it][ef][f]);
      }

      // write next tile into other buffer (no barrier needed: disjoint buf)
      if (jt + 1 < 32) {
        *(h8*)((char*)&Ks[cur ^ 1][0][0] + (kr << 7) + ((kc ^ (kr & 7)) << 4)) = kreg;
        *(h8*)((char*)&Vts[cur ^ 1][0][0] + (vr << 6) + ((vc ^ ((vr >> 1) & 3)) << 4)) = vreg;
      }
    }
  }

  // epilogue: lane (p,g): col i, rows e = ef*16+4g+r -> float4
#pragma unroll
  for (int it = 0; it < 2; ++it) {
#pragma unroll
    for (int f = 0; f < 2; ++f) {
      const int i = i0 + it * 128 + w * 32 + f * 16 + p;
#pragma unroll
      for (int ef = 0; ef < 4; ++ef) {
        float4 o4 = {oacc[it][ef][f][0], oacc[it][ef][f][1], oacc[it][ef][f][2], oacc[it][ef][f][3]};
        *(float4*)&Out[((size_t)b * NN + i) * EMB + h * HD + ef * 16 + 4 * g] = o4;
      }
    }
  }
}

extern "C" void kernel_launch(void* const* d_in, const int* in_sizes, int n_in,
                              void* d_out, int out_size, void* d_ws, size_t ws_size,
                              hipStream_t stream) {
  const float* X  = (const float*)d_in[0];
  const float* Wq = (const float*)d_in[1];
  const float* bq = (const float*)d_in[2];
  const float* Wk = (const float*)d_in[3];
  const float* bk = (const float*)d_in[4];
  const float* Wv = (const float*)d_in[5];
  const float* bv = (const float*)d_in[6];

  // workspace layout (~156.1 MB)
  char* ws = (char*)d_ws;
  _Float16* Qw = (_Float16*)(ws);                  // 50,331,648 B
  _Float16* Kw = (_Float16*)(ws + 50331648);       // 50,331,648 B
  _Float16* Vt = (_Float16*)(ws + 100663296);      // 50,331,648 B
  _Float16* Wt = (_Float16*)(ws + 150994944);      // 3 * 1,179,648 B
  float* MT    = (float*)(ws + 154533888);         // 12,288 B

  // transients inside d_out (overwritten by final f32 result at the end)
  _Float16* Xh   = (_Float16*)d_out;                        // 50,331,648 B
  _Float16* Vtmp = (_Float16*)((char*)d_out + 50331648);    // 50,331,648 B
  float* Out = (float*)d_out;

  k_cvt<<<dim3(6291456 / 256), 256, 0, stream>>>(X, Xh, 6291456);
  k_wt<<<dim3(12, 12, 3), 256, 0, stream>>>(Wq, Wk, Wv, Wt);
  k_projf<<<dim3(18, 256), 256, 0, stream>>>(Xh, Wt, bq, bk, bv, Qw, Kw, Vtmp);
  k_stats<<<dim3(8, 384), 256, 0, stream>>>(Qw, Kw, Vtmp, MT, Vt);
  k_out<<<dim3(8, 192), 256, 0, stream>>>(Qw, Kw, Vt, MT, Out);
}

// Round 10
// 386.408 us; speedup vs baseline: 1.0349x; 1.0349x over previous
//
#include <hip/hip_runtime.h>

#define EMB 768
#define NH 12
#define HD 64
#define BB 32
#define NN 1024
// log2(e)/sqrt(12): Q pre-scale so QK^T is in log2 domain
#define QSCALE 0.41647025f

typedef _Float16 h8 __attribute__((ext_vector_type(8)));
typedef _Float16 h4 __attribute__((ext_vector_type(4)));
typedef _Float16 h2 __attribute__((ext_vector_type(2)));
typedef float f4 __attribute__((ext_vector_type(4)));

static __device__ __forceinline__ f4 mfma16(h8 a, h8 b, f4 c) {
  return __builtin_amdgcn_mfma_f32_16x16x32_f16(a, b, c, 0, 0, 0);
}

static __device__ __forceinline__ h2 cvt_pk(float a, float b) {
  return __builtin_bit_cast(h2, __builtin_amdgcn_cvt_pkrtz(a, b));
}

static __device__ __forceinline__ float exp2a(float x) {
#if __has_builtin(__builtin_amdgcn_exp2f)
  return __builtin_amdgcn_exp2f(x);
#else
  float r;
  asm("v_exp_f32 %0, %1\n\ts_nop 1" : "=v"(r) : "v"(x));
  return r;
#endif
}

// async global->LDS, 16B per lane; LDS dest = wave-uniform base + lane*16
static __device__ __forceinline__ void gload16(const _Float16* g, _Float16* lds) {
  __builtin_amdgcn_global_load_lds(
      (const __attribute__((address_space(1))) void*)g,
      (__attribute__((address_space(3))) void*)lds, 16, 0, 0);
}

// ---------------- X f32 -> f16 ----------------
__global__ __launch_bounds__(256) void k_cvt(const float* __restrict__ X,
                                             _Float16* __restrict__ Xh, int n4) {
  int i = blockIdx.x * 256 + threadIdx.x;
  if (i >= n4) return;
  float4 v = ((const float4*)X)[i];
  h4 o = {(_Float16)v.x, (_Float16)v.y, (_Float16)v.z, (_Float16)v.w};
  ((h4*)Xh)[i] = o;
}

// ---------------- W (768x768 f32) -> W^T f16, all three ----------------
__global__ __launch_bounds__(256) void k_wt(const float* __restrict__ W0,
                                            const float* __restrict__ W1,
                                            const float* __restrict__ W2,
                                            _Float16* __restrict__ Wt) {
  const float* W = blockIdx.z == 0 ? W0 : (blockIdx.z == 1 ? W1 : W2);
  _Float16* dst = Wt + (size_t)blockIdx.z * EMB * EMB;
  __shared__ float tile[64][65];
  const int t = threadIdx.x;
  const int r0 = blockIdx.y * 64, c0 = blockIdx.x * 64;
  const int r = t >> 4, c4 = (t & 15) * 4;
#pragma unroll
  for (int i = 0; i < 4; ++i) {
    const float4 v = *(const float4*)&W[(size_t)(r0 + r + 16 * i) * EMB + c0 + c4];
    tile[r + 16 * i][c4 + 0] = v.x; tile[r + 16 * i][c4 + 1] = v.y;
    tile[r + 16 * i][c4 + 2] = v.z; tile[r + 16 * i][c4 + 3] = v.w;
  }
  __syncthreads();
  const int cc = t >> 2, rr = (t & 3) * 16;
#pragma unroll
  for (int half = 0; half < 2; ++half) {
    h8 o;
#pragma unroll
    for (int j = 0; j < 8; ++j) o[j] = (_Float16)tile[rr + half * 8 + j][cc];
    *(h8*)&dst[(size_t)(c0 + cc) * EMB + r0 + rr + half * 8] = o;
  }
}

// ---------------- fused QKV GEMM: [32768 x 768] @ [768 x 2304] ----------------
// m97-pattern: BK=64, double-buffered LDS via global_load_lds w16,
// linear LDS + inverse-swizzled global source + swizzled ds_read_b128 (rule #21).
__global__ __launch_bounds__(256) void k_projf(const _Float16* __restrict__ Xh,
                                               const _Float16* __restrict__ Wt,
                                               const float* __restrict__ bq,
                                               const float* __restrict__ bk,
                                               const float* __restrict__ bv,
                                               _Float16* __restrict__ Qw,
                                               _Float16* __restrict__ Kw,
                                               _Float16* __restrict__ Vtmp) {
  __shared__ _Float16 As[2][128 * 64];  // 16KB per buf
  __shared__ _Float16 Bs[2][128 * 64];
  const int t = threadIdx.x;
  const int w = t >> 6, l = t & 63;
  const int wm = w >> 1, wn = w & 1;
  const int p = l & 15, g = l >> 4;
  const int by = blockIdx.x;            // n-tile 0..17
  const int m0 = blockIdx.y * 128;      // m-tile 0..255
  const int n0 = by * 128;              // into flat Wt [2304][768]

  f4 acc[4][4];
#pragma unroll
  for (int mf = 0; mf < 4; ++mf)
#pragma unroll
    for (int nf = 0; nf < 4; ++nf) acc[mf][nf] = f4{0.f, 0.f, 0.f, 0.f};

  // staging geometry: lane l covers row (l>>3) of its 8-row segment, chunk (l&7)
  const int lrow = l >> 3, lch = (l & 7) ^ (l >> 3);  // inverse-swizzled source chunk

#define STAGE(buf, k0)                                                            \
  {                                                                               \
    _Float16* ab = &As[buf][0];                                                   \
    _Float16* bb = &Bs[buf][0];                                                   \
    _Pragma("unroll") for (int i = 0; i < 4; ++i) {                               \
      const int seg = (w << 2) | i;                                               \
      const int grow = (seg << 3) | lrow;                                         \
      gload16(Xh + (size_t)(m0 + grow) * EMB + (k0) + lch * 8, ab + seg * 512);   \
      gload16(Wt + (size_t)(n0 + grow) * EMB + (k0) + lch * 8, bb + seg * 512);   \
    }                                                                             \
  }

  STAGE(0, 0)
  __syncthreads();

  int cur = 0;
  for (int kt = 0; kt < 12; ++kt) {
    if (kt + 1 < 12) STAGE(cur ^ 1, (kt + 1) * 64)
    const char* asb = (const char*)&As[cur][0];
    const char* bsb = (const char*)&Bs[cur][0];
#pragma unroll
    for (int ks = 0; ks < 2; ++ks) {
      h8 af[4], bf[4];
#pragma unroll
      for (int mf = 0; mf < 4; ++mf)
        af[mf] = *(const h8*)(asb + ((wm * 64 + mf * 16 + p) << 7) +
                              ((((ks << 2) | g) ^ (p & 7)) << 4));
#pragma unroll
      for (int nf = 0; nf < 4; ++nf)
        bf[nf] = *(const h8*)(bsb + ((wn * 64 + nf * 16 + p) << 7) +
                              ((((ks << 2) | g) ^ (p & 7)) << 4));
#pragma unroll
      for (int mf = 0; mf < 4; ++mf)
#pragma unroll
        for (int nf = 0; nf < 4; ++nf) acc[mf][nf] = mfma16(af[mf], bf[nf], acc[mf][nf]);
    }
    __syncthreads();
    cur ^= 1;
  }
#undef STAGE

  // epilogue: z-select (tiles never straddle the 768 boundary: 768 % 128 == 0)
  const int z = by / 6;
  const int nl0 = (by % 6) * 128;
  const float* bias = z == 0 ? bq : (z == 1 ? bk : bv);
  _Float16* Outz = z == 0 ? Qw : (z == 1 ? Kw : Vtmp);
  const float scale = z == 0 ? QSCALE : 1.0f;
#pragma unroll
  for (int nf = 0; nf < 4; ++nf) {
    const int C = nl0 + wn * 64 + nf * 16 + p;
    const float bvv = bias[C];
    const int h = C >> 6, e = C & 63;
#pragma unroll
    for (int mf = 0; mf < 4; ++mf) {
#pragma unroll
      for (int r = 0; r < 4; ++r) {
        const int R = m0 + wm * 64 + mf * 16 + g * 4 + r;
        const int b = R >> 10, tok = R & 1023;
        Outz[((size_t)(b * NH + h) * NN + tok) * HD + e] = (_Float16)((acc[mf][nf][r] + bvv) * scale);
      }
    }
  }
}

// ---------------- column stats + fused V scale/transpose ----------------
// l~_j = sum_i 2^S'; MT = log2(max_j l~); Vt[bh][e][j] = V[bh][j][e] * 2^MT / l~_j
__global__ __launch_bounds__(256) void k_stats(const _Float16* __restrict__ Q,
                                               const _Float16* __restrict__ K,
                                               const _Float16* __restrict__ Vtmp,
                                               float* __restrict__ MT,
                                               _Float16* __restrict__ Vt) {
  const int bh = blockIdx.x * 48 + (blockIdx.y >> 3);   // XCD-aware: bx = XCD
  const int jt = blockIdx.y & 7;
  const int j0 = jt * 128;
  __shared__ __align__(16) char SMEM[35080];
  _Float16* Ks = (_Float16*)SMEM;              // 16KB [128][64] swizzled
  _Float16* Qs = (_Float16*)(SMEM + 16384);    // 16KB
  float* Lj    = (float*)(SMEM + 32768);       // 512B
  float* reds  = (float*)(SMEM + 33280);       // 1KB [2][128]
  float* MsShp = (float*)(SMEM + 34312);       // 4B
  _Float16 (*Vtile)[72] = (_Float16(*)[72])SMEM;  // alias Ks after main loop: [64][72]=9216B
  const _Float16* Qb = Q + (size_t)bh * NN * HD;
  const _Float16* Kb = K + (size_t)bh * NN * HD;
  const int t = threadIdx.x, w = t >> 6, l = t & 63;
  const int wi = w >> 1, wj = w & 1;
  const int p = l & 15, g = l >> 4;
  // staging geometry (same as k_projf)
  const int lrow = l >> 3, lch = (l & 7) ^ (l >> 3);

  // K tile staged once
#pragma unroll
  for (int i = 0; i < 4; ++i) {
    const int seg = (w << 2) | i;
    const int grow = (seg << 3) | lrow;
    gload16(Kb + (size_t)(j0 + grow) * HD + lch * 8, Ks + seg * 512);
  }
  if (t < 128) Lj[t] = 0.f;
  __syncthreads();

  const char* ksb = (const char*)Ks;
  const char* qsb = (const char*)Qs;
  for (int i0 = 0; i0 < NN; i0 += 128) {
#pragma unroll
    for (int i = 0; i < 4; ++i) {
      const int seg = (w << 2) | i;
      const int grow = (seg << 3) | lrow;
      gload16(Qb + (size_t)(i0 + grow) * HD + lch * 8, Qs + seg * 512);
    }
    __syncthreads();  // drains gload: Qs ready
    f4 s[4][4];
#pragma unroll
    for (int mf = 0; mf < 4; ++mf)
#pragma unroll
      for (int nf = 0; nf < 4; ++nf) s[mf][nf] = f4{0.f, 0.f, 0.f, 0.f};
#pragma unroll
    for (int ks = 0; ks < 2; ++ks) {
      h8 af[4], bf[4];
#pragma unroll
      for (int mf = 0; mf < 4; ++mf)
        af[mf] = *(const h8*)(qsb + ((wi * 64 + mf * 16 + p) << 7) + ((((ks << 2) | g) ^ (p & 7)) << 4));
#pragma unroll
      for (int nf = 0; nf < 4; ++nf)
        bf[nf] = *(const h8*)(ksb + ((wj * 64 + nf * 16 + p) << 7) + ((((ks << 2) | g) ^ (p & 7)) << 4));
#pragma unroll
      for (int mf = 0; mf < 4; ++mf)
#pragma unroll
        for (int nf = 0; nf < 4; ++nf) s[mf][nf] = mfma16(af[mf], bf[nf], s[mf][nf]);
    }
    // direct f32 exp-sum over i (no max needed: |S'| bounded, f32 range ample)
#pragma unroll
    for (int nf = 0; nf < 4; ++nf) {
      float cs = 0.f;
#pragma unroll
      for (int mf = 0; mf < 4; ++mf)
#pragma unroll
        for (int r = 0; r < 4; ++r) cs += exp2a(s[mf][nf][r]);
      cs += __shfl_xor(cs, 16);
      cs += __shfl_xor(cs, 32);
      if (l < 16) reds[wi * 128 + wj * 64 + nf * 16 + l] = cs;
    }
    __syncthreads();
    if (t < 128) Lj[t] += reds[t] + reds[128 + t];
    __syncthreads();  // also guards Qs overwrite next iter
  }
  // tail: M* = log2(max_j l~_j)  (guarantees P = 2^(S'-M*) <= 1)
  if (w == 0) {
    float mv = fmaxf(Lj[l], Lj[l + 64]);
#pragma unroll
    for (int d = 32; d; d >>= 1) mv = fmaxf(mv, __shfl_xor(mv, d));
    if (l == 0) { MsShp[0] = __log2f(mv); MT[bh * 8 + jt] = MsShp[0]; }
  }
  __syncthreads();
  const float rmsc = exp2a(MsShp[0]);  // 2^M*;  V' = V * 2^M* / l~_j

  // fused V scale + transpose: rows j0..j0+127, two 64-row halves via Vtile (aliases Ks)
  const _Float16* Vb = Vtmp + (size_t)bh * NN * HD;
  _Float16* Vo = Vt + (size_t)bh * HD * NN;
  const int jr = t >> 3, c8 = (t & 7) * 8;
#pragma unroll
  for (int half = 0; half < 2; ++half) {
#pragma unroll
    for (int i = 0; i < 2; ++i) {
      const int jl = half * 64 + jr + 32 * i;
      const float inv = rmsc / Lj[jl];
      h8 v = *(const h8*)&Vb[(size_t)(j0 + jl) * HD + c8];
      h8 o;
#pragma unroll
      for (int j = 0; j < 8; ++j) o[j] = (_Float16)((float)v[j] * inv);
      *(h8*)&Vtile[jr + 32 * i][c8] = o;
    }
    __syncthreads();
#pragma unroll
    for (int i = 0; i < 2; ++i) {
      h8 o;
#pragma unroll
      for (int j = 0; j < 8; ++j) o[j] = Vtile[c8 + j][jr + 32 * i];
      *(h8*)&Vo[(size_t)(jr + 32 * i) * NN + j0 + half * 64 + c8] = o;
    }
    __syncthreads();
  }
}

// ---------------- output: out = 2^(S' - M*) @ V'  (S^T trick; 2 i-tiles/block; unroll-4) ---------
__global__ __launch_bounds__(256) void k_out(const _Float16* __restrict__ Q,
                                             const _Float16* __restrict__ K,
                                             const _Float16* __restrict__ Vt,
                                             const float* __restrict__ MT,
                                             float* __restrict__ Out) {
  const int bh = blockIdx.x * 48 + (blockIdx.y >> 2);   // XCD-aware: bx = XCD
  const int i0 = (blockIdx.y & 3) * 256;
  const int b = bh / NH, h = bh % NH;
  __shared__ _Float16 Ks[2][32][64];      // [buf][j][e], 128B rows, swz mask 7
  __shared__ _Float16 Vts[2][64][32];     // [buf][e][j], 64B rows, swz (row>>1)&3
  __shared__ _Float16 Ps[4][2][32][32];   // [wave][it][i][j], wave-private
  const _Float16* Qb = Q + (size_t)bh * NN * HD;
  const _Float16* Kb = K + (size_t)bh * NN * HD;
  const _Float16* Vb = Vt + (size_t)bh * HD * NN;
  const int t = threadIdx.x, w = t >> 6, l = t & 63;
  const int p = l & 15, g = l >> 4;
  char* psb[2] = {(char*)&Ps[w][0][0][0], (char*)&Ps[w][1][0][0]};

  // Q B-frags for both i-tiles (col i = i0 + it*128 + w*32 + f*16 + p)
  h8 bq[2][2][2];
#pragma unroll
  for (int it = 0; it < 2; ++it)
#pragma unroll
    for (int f = 0; f < 2; ++f)
#pragma unroll
      for (int ks = 0; ks < 2; ++ks)
        bq[it][f][ks] = *(const h8*)&Qb[(size_t)(i0 + it * 128 + w * 32 + f * 16 + p) * HD + ks * 32 + g * 8];

  f4 oacc[2][4][2];  // [it][ef][if] -> D[e][i]
#pragma unroll
  for (int it = 0; it < 2; ++it)
#pragma unroll
    for (int ef = 0; ef < 4; ++ef)
#pragma unroll
      for (int f = 0; f < 2; ++f) oacc[it][ef][f] = f4{0.f, 0.f, 0.f, 0.f};

  // staging: K 32x64 (row kr, chunk kc), V 64x32 (row vr, chunk vc)
  const int kr = t >> 3, kc = t & 7;
  const int vr = t >> 2, vc = t & 3;

  h8 kreg = *(const h8*)&Kb[(size_t)kr * HD + kc * 8];
  h8 vreg = *(const h8*)&Vb[(size_t)vr * NN + vc * 8];
  *(h8*)((char*)&Ks[0][0][0] + (kr << 7) + ((kc ^ (kr & 7)) << 4)) = kreg;
  *(h8*)((char*)&Vts[0][0][0] + (vr << 6) + ((vc ^ ((vr >> 1) & 3)) << 4)) = vreg;

  for (int jt4 = 0; jt4 < 8; ++jt4) {
    const float Mstar = MT[bh * 8 + jt4];
#pragma unroll
    for (int u = 0; u < 4; ++u) {
      const int jt = jt4 * 4 + u;
      const int cur = u & 1;  // jt4*4 even -> jt&1 == u&1 (static)
      char* ksb = (char*)&Ks[cur][0][0];
      char* vsb = (char*)&Vts[cur][0][0];
      __syncthreads();  // staged buf[cur] visible; prev reads of buf[cur^1] done
      if (jt + 1 < 32) {
        const int j0n = (jt + 1) * 32;
        kreg = *(const h8*)&Kb[(size_t)(j0n + kr) * HD + kc * 8];
        vreg = *(const h8*)&Vb[(size_t)vr * NN + j0n + vc * 8];
      }

      // shared fragments (reused by both i-tiles)
      h8 ak[2][2], av[4];
#pragma unroll
      for (int ks = 0; ks < 2; ++ks)
#pragma unroll
        for (int jf = 0; jf < 2; ++jf)
          ak[ks][jf] = *(const h8*)(ksb + ((jf * 16 + p) << 7) + ((((ks << 2) | g) ^ (p & 7)) << 4));
#pragma unroll
      for (int ef = 0; ef < 4; ++ef)
        av[ef] = *(const h8*)(vsb + ((ef * 16 + p) << 6) + ((g ^ ((p >> 1) & 3)) << 4));

      // per i-tile: S'^T, exp, P write
#pragma unroll
      for (int it = 0; it < 2; ++it) {
        f4 s[2][2];
#pragma unroll
        for (int f = 0; f < 2; ++f)
#pragma unroll
          for (int jf = 0; jf < 2; ++jf) s[f][jf] = f4{-Mstar, -Mstar, -Mstar, -Mstar};
#pragma unroll
        for (int ks = 0; ks < 2; ++ks)
#pragma unroll
          for (int f = 0; f < 2; ++f)
#pragma unroll
            for (int jf = 0; jf < 2; ++jf) s[f][jf] = mfma16(ak[ks][jf], bq[it][f][ks], s[f][jf]);
#pragma unroll
        for (int f = 0; f < 2; ++f)
#pragma unroll
          for (int jf = 0; jf < 2; ++jf) {
            const f4 sv = s[f][jf];
            h2 lo = cvt_pk(exp2a(sv[0]), exp2a(sv[1]));
            h2 hi = cvt_pk(exp2a(sv[2]), exp2a(sv[3]));
            h4 pw; pw[0] = lo[0]; pw[1] = lo[1]; pw[2] = hi[0]; pw[3] = hi[1];
            *(h4*)(psb[it] + ((f * 16 + p) << 6) +
                   (((2 * jf + (g >> 1)) ^ ((p >> 1) & 3)) << 4) + ((g & 1) << 3)) = pw;
          }
      }
      // wave-private P: DS in-order per wave; insurance wait + scheduling fence
      asm volatile("s_waitcnt lgkmcnt(0)" ::: "memory");
      __builtin_amdgcn_sched_barrier(0);

      // PV for both i-tiles
#pragma unroll
      for (int it = 0; it < 2; ++it) {
        h8 bp[2];
#pragma unroll
        for (int f = 0; f < 2; ++f)
          bp[f] = *(const h8*)(psb[it] + ((f * 16 + p) << 6) + ((g ^ ((p >> 1) & 3)) << 4));
#pragma unroll
        for (int ef = 0; ef < 4; ++ef)
#pragma unroll
          for (int f = 0; f < 2; ++f) oacc[it][ef][f] = mfma16(av[ef], bp[f], oacc[it][ef][f]);
      }

      // write next tile into other buffer (no barrier needed: disjoint buf)
      if (jt + 1 < 32) {
        *(h8*)((char*)&Ks[cur ^ 1][0][0] + (kr << 7) + ((kc ^ (kr & 7)) << 4)) = kreg;
        *(h8*)((char*)&Vts[cur ^ 1][0][0] + (vr << 6) + ((vc ^ ((vr >> 1) & 3)) << 4)) = vreg;
      }
    }
  }

  // epilogue: lane (p,g): col i, rows e = ef*16+4g+r -> float4
#pragma unroll
  for (int it = 0; it < 2; ++it) {
#pragma unroll
    for (int f = 0; f < 2; ++f) {
      const int i = i0 + it * 128 + w * 32 + f * 16 + p;
#pragma unroll
      for (int ef = 0; ef < 4; ++ef) {
        float4 o4 = {oacc[it][ef][f][0], oacc[it][ef][f][1], oacc[it][ef][f][2], oacc[it][ef][f][3]};
        *(float4*)&Out[((size_t)b * NN + i) * EMB + h * HD + ef * 16 + 4 * g] = o4;
      }
    }
  }
}

extern "C" void kernel_launch(void* const* d_in, const int* in_sizes, int n_in,
                              void* d_out, int out_size, void* d_ws, size_t ws_size,
                              hipStream_t stream) {
  const float* X  = (const float*)d_in[0];
  const float* Wq = (const float*)d_in[1];
  const float* bq = (const float*)d_in[2];
  const float* Wk = (const float*)d_in[3];
  const float* bk = (const float*)d_in[4];
  const float* Wv = (const float*)d_in[5];
  const float* bv = (const float*)d_in[6];

  // workspace layout (~154.5 MB)
  char* ws = (char*)d_ws;
  _Float16* Qw = (_Float16*)(ws);                  // 50,331,648 B
  _Float16* Kw = (_Float16*)(ws + 50331648);       // 50,331,648 B
  _Float16* Vt = (_Float16*)(ws + 100663296);      // 50,331,648 B
  _Float16* Wt = (_Float16*)(ws + 150994944);      // 3 * 1,179,648 B
  float* MT    = (float*)(ws + 154533888);         // 12,288 B

  // transients inside d_out (overwritten by final f32 result at the end)
  _Float16* Xh   = (_Float16*)d_out;                        // 50,331,648 B
  _Float16* Vtmp = (_Float16*)((char*)d_out + 50331648);    // 50,331,648 B
  float* Out = (float*)d_out;

  k_cvt<<<dim3(6291456 / 256), 256, 0, stream>>>(X, Xh, 6291456);
  k_wt<<<dim3(12, 12, 3), 256, 0, stream>>>(Wq, Wk, Wv, Wt);
  k_projf<<<dim3(18, 256), 256, 0, stream>>>(Xh, Wt, bq, bk, bv, Qw, Kw, Vtmp);
  k_stats<<<dim3(8, 384), 256, 0, stream>>>(Qw, Kw, Vtmp, MT, Vt);
  k_out<<<dim3(8, 192), 256, 0, stream>>>(Qw, Kw, Vt, MT, Out);
}